// Round 3
// baseline (139.801 us; speedup 1.0000x reference)
//
#include <hip/hip_runtime.h>

#define TLEN 8192
#define DD   4096
#define NF   10
#define NC   12   // 10 a_f coeffs + g + pad
#define NACC 12   // x_sum, pooled, h_f (f=0..9)

// ---------- helpers ----------
__device__ __forceinline__ double powi_d(double w, int n) {
    double a = 1.0, p = w;
    while (n) { if (n & 1) a *= p; p *= p; n >>= 1; }
    return a;
}

// ---------- kernel 1: fused coef + streaming pass over inp ----------
// Block (bx, by): columns [bx*1024, bx*1024+1024), rows [by*rows, (by+1)*rows).
// Prologue computes the per-row coefficient table in LDS (fp64, spread over
// all threads). Main loop: 2-group x 4-row software pipeline (8 outstanding
// float4 loads per wave).
// Partials: part[(by*NC + acc)*DD + d], acc 0=x_sum, 1=pooled_raw, 2+f=h_f.
__global__ __launch_bounds__(256) void pass_kernel(const float* __restrict__ inp,
                                                   const float* __restrict__ w,
                                                   const float* __restrict__ pool_w,
                                                   float* __restrict__ part,
                                                   int rows) {
    __shared__ float sc[256 * NC];   // per-row coeffs (a_0..a_9, g, pad)
    __shared__ float scg[256 * NF];  // per-(row,f) pooled partial
    const int t0 = blockIdx.y * rows;

    // --- coefficient prologue (rows <= 256 guaranteed by launcher) ---
    for (int i = threadIdx.x; i < rows * NF; i += 256) {
        int r = i / NF, f = i - r * NF;
        double wf = (double)w[(size_t)f * DD];   // broadcast along D
        int n = TLEN - 1 - (t0 + r);
        double a = powi_d(wf, n);
        double den = 1.0 - wf;
        sc[r * NC + f] = (float)a;
        scg[i] = (float)((den > 1e-12) ? (double)pool_w[f] * (1.0 - a) / den
                                       : (double)pool_w[f] * (double)n);
    }
    __syncthreads();
    if (threadIdx.x < rows) {
        float g = 0.0f;
#pragma unroll
        for (int f = 0; f < NF; ++f) g += scg[threadIdx.x * NF + f];
        sc[threadIdx.x * NC + NF] = g;
    }
    __syncthreads();

    const int d = blockIdx.x * 1024 + threadIdx.x * 4;

    float sx=0,sy=0,sz=0,sw=0;           // x_sum
    float px=0,py=0,pz=0,pw4=0;          // pooled_raw
    float hx[NF], hy[NF], hz[NF], hw[NF];
#pragma unroll
    for (int f = 0; f < NF; ++f) { hx[f]=0; hy[f]=0; hz[f]=0; hw[f]=0; }

    auto PROC = [&](int r, float4 x) {
        const float* cf = &sc[r * NC];
        sx += x.x; sy += x.y; sz += x.z; sw += x.w;
        float g = cf[NF];
        px  = fmaf(g, x.x, px);  py  = fmaf(g, x.y, py);
        pz  = fmaf(g, x.z, pz);  pw4 = fmaf(g, x.w, pw4);
#pragma unroll
        for (int f = 0; f < NF; ++f) {
            float a = cf[f];
            hx[f] = fmaf(a, x.x, hx[f]); hy[f] = fmaf(a, x.y, hy[f]);
            hz[f] = fmaf(a, x.z, hz[f]); hw[f] = fmaf(a, x.w, hw[f]);
        }
    };

    const float* ip = inp + (size_t)t0 * DD + d;
    // rows is a multiple of 4 and >= 8 for all launcher choices
    float4 xa = *(const float4*)(ip);
    float4 xb = *(const float4*)(ip + DD);
    float4 xc = *(const float4*)(ip + 2 * DD);
    float4 xd = *(const float4*)(ip + 3 * DD);
    ip += 4 * (size_t)DD;
    int r = 0;
    for (; r + 4 < rows; r += 4) {
        float4 ya = *(const float4*)(ip);
        float4 yb = *(const float4*)(ip + DD);
        float4 yc = *(const float4*)(ip + 2 * DD);
        float4 yd = *(const float4*)(ip + 3 * DD);
        ip += 4 * (size_t)DD;
        PROC(r + 0, xa); PROC(r + 1, xb); PROC(r + 2, xc); PROC(r + 3, xd);
        xa = ya; xb = yb; xc = yc; xd = yd;
    }
    PROC(r + 0, xa); PROC(r + 1, xb); PROC(r + 2, xc); PROC(r + 3, xd);

    size_t base = ((size_t)blockIdx.y * NC) * DD + d;
    *(float4*)(part + base)      = make_float4(sx, sy, sz, sw);
    *(float4*)(part + base + DD) = make_float4(px, py, pz, pw4);
#pragma unroll
    for (int f = 0; f < NF; ++f)
        *(float4*)(part + base + (size_t)(2 + f) * DD) =
            make_float4(hx[f], hy[f], hz[f], hw[f]);
}

// ---------- kernel 2: reduce partials over chunks ----------
__global__ void reduce_kernel(const float* __restrict__ part,
                              float* __restrict__ red, int C) {
    int idx = blockIdx.x * blockDim.x + threadIdx.x;  // 0 .. 12*4096
    if (idx >= NACC * DD) return;
    float s = 0.0f;
    for (int c = 0; c < C; ++c)
        s += part[(size_t)c * NC * DD + idx];
    red[idx] = s;
}

// ---------- kernel 3: finalize h_final + avg vector ----------
__global__ void finalize_kernel(const float* __restrict__ red,
                                const float* __restrict__ w,
                                const float* __restrict__ pool_w,
                                const float* __restrict__ pool_b,
                                const float* __restrict__ hidden,
                                float* __restrict__ out,
                                float* __restrict__ avg) {
    int i = blockIdx.x * blockDim.x + threadIdx.x;   // 0..1023
    int d = i * 4;
    float4 xs = *(const float4*)(red + d);
    float4 pl = *(const float4*)(red + DD + d);
    const float invT = 1.0f / (float)TLEN;
#pragma unroll
    for (int f = 0; f < NF; ++f) {
        double wf = (double)w[(size_t)f * DD];
        double wTd = powi_d(wf, TLEN);
        double den = 1.0 - wf;
        double sTd = (den > 1e-12) ? (1.0 - wTd) / den : (double)TLEN;
        float wT = (float)wTd;
        float pwsT = (float)((double)pool_w[f] * sTd);
        float4 hf = *(const float4*)(red + (size_t)(2 + f) * DD + d);
        float4 h0 = *(const float4*)(hidden + (size_t)f * DD + d);
        hf.x = fmaf(wT, h0.x, hf.x); hf.y = fmaf(wT, h0.y, hf.y);
        hf.z = fmaf(wT, h0.z, hf.z); hf.w = fmaf(wT, h0.w, hf.w);
        pl.x = fmaf(pwsT, h0.x, pl.x); pl.y = fmaf(pwsT, h0.y, pl.y);
        pl.z = fmaf(pwsT, h0.z, pl.z); pl.w = fmaf(pwsT, h0.w, pl.w);
        float* o = out + 10 + (size_t)f * DD + d;   // 40B-misaligned -> scalar
        o[0] = hf.x; o[1] = hf.y; o[2] = hf.z; o[3] = hf.w;
    }
    float pb = pool_b[0];
    avg[d+0] = xs.x * invT; avg[d+1] = xs.y * invT;
    avg[d+2] = xs.z * invT; avg[d+3] = xs.w * invT;
    avg[DD + d + 0] = pl.x * invT + pb; avg[DD + d + 1] = pl.y * invT + pb;
    avg[DD + d + 2] = pl.z * invT + pb; avg[DD + d + 3] = pl.w * invT + pb;
}

// ---------- kernel 4: GEMV  hid = relu(i2o_w @ avg + i2o_b) ----------
// avg staged in LDS once per block; one wave per output row.
__global__ __launch_bounds__(256) void gemv_kernel(const float* __restrict__ W,
                                                   const float* __restrict__ b,
                                                   const float* __restrict__ avg,
                                                   float* __restrict__ hid) {
    __shared__ float sa[2 * DD];
    for (int i = threadIdx.x * 4; i < 2 * DD; i += 1024)
        *(float4*)(sa + i) = *(const float4*)(avg + i);
    __syncthreads();
    int row  = blockIdx.x * 4 + (threadIdx.x >> 6);
    int lane = threadIdx.x & 63;
    const float* wr = W + (size_t)row * (2 * DD) + lane * 4;
    const float* ar = sa + lane * 4;
    float acc0 = 0.0f, acc1 = 0.0f;
#pragma unroll 8
    for (int g = 0; g < 32; g += 2) {
        float4 w0 = *(const float4*)(wr + g * 256);
        float4 w1 = *(const float4*)(wr + g * 256 + 256);
        float4 a0 = *(const float4*)(ar + g * 256);
        float4 a1 = *(const float4*)(ar + g * 256 + 256);
        acc0 = fmaf(w0.x, a0.x, acc0); acc0 = fmaf(w0.y, a0.y, acc0);
        acc0 = fmaf(w0.z, a0.z, acc0); acc0 = fmaf(w0.w, a0.w, acc0);
        acc1 = fmaf(w1.x, a1.x, acc1); acc1 = fmaf(w1.y, a1.y, acc1);
        acc1 = fmaf(w1.z, a1.z, acc1); acc1 = fmaf(w1.w, a1.w, acc1);
    }
    float acc = acc0 + acc1;
    for (int off = 32; off; off >>= 1) acc += __shfl_down(acc, off, 64);
    if (lane == 0) hid[row] = fmaxf(acc + b[row], 0.0f);
}

// ---------- kernel 5: final 10-way dot ----------
__global__ void out_kernel(const float* __restrict__ hid,
                           const float* __restrict__ ow,
                           const float* __restrict__ ob,
                           float* __restrict__ out) {
    __shared__ float redl[256];
    int o = blockIdx.x;
    float acc = 0.0f;
    for (int h = threadIdx.x; h < DD; h += 256)
        acc = fmaf(hid[h], ow[(size_t)o * DD + h], acc);
    redl[threadIdx.x] = acc;
    __syncthreads();
    for (int s = 128; s; s >>= 1) {
        if (threadIdx.x < s) redl[threadIdx.x] += redl[threadIdx.x + s];
        __syncthreads();
    }
    if (threadIdx.x == 0) out[o] = redl[0] + ob[o];
}

extern "C" void kernel_launch(void* const* d_in, const int* in_sizes, int n_in,
                              void* d_out, int out_size, void* d_ws, size_t ws_size,
                              hipStream_t stream) {
    const float* inp    = (const float*)d_in[0];
    const float* hidden = (const float*)d_in[1];
    const float* w      = (const float*)d_in[2];
    const float* pw     = (const float*)d_in[3];
    const float* pb     = (const float*)d_in[4];
    const float* i2o_w  = (const float*)d_in[5];
    const float* i2o_b  = (const float*)d_in[6];
    const float* o_w    = (const float*)d_in[7];
    const float* o_b    = (const float*)d_in[8];
    float* out = (float*)d_out;
    float* ws  = (float*)d_ws;

    // workspace layout (floats)
    float* red  = ws;                 // 12*4096 = 49152
    float* avg  = ws + 49152;         // 8192
    float* hid  = ws + 57344;         // 4096
    float* part = ws + 61440;         // C*12*4096

    // chunk count: prefer 256 (4 blocks/CU); shrink if workspace is small.
    int C = 256;
    while (C > 32) {
        size_t need = (61440 + (size_t)C * NC * DD) * sizeof(float);
        if (need <= ws_size) break;
        C >>= 1;
    }
    int rows = TLEN / C;   // 32..256, multiple of 4

    pass_kernel<<<dim3(4, C), 256, 0, stream>>>(inp, w, pw, part, rows);
    reduce_kernel<<<(NACC * DD + 255) / 256, 256, 0, stream>>>(part, red, C);
    finalize_kernel<<<4, 256, 0, stream>>>(red, w, pw, pb, hidden, out, avg);
    gemv_kernel<<<DD / 4, 256, 0, stream>>>(i2o_w, i2o_b, avg, hid);
    out_kernel<<<10, 256, 0, stream>>>(hid, o_w, o_b, out);
}

// Round 4
// 131.527 us; speedup vs baseline: 1.0629x; 1.0629x over previous
//
#include <hip/hip_runtime.h>

#define TLEN 8192
#define DD   4096
#define NF   10
#define NC   12   // 10 a_f coeffs + g + pad
#define NACC 12   // x_sum, pooled, h_f (f=0..9)

// ---------- helpers ----------
__device__ __forceinline__ double powi_d(double w, int n) {
    double a = 1.0, p = w;
    while (n) { if (n & 1) a *= p; p *= p; n >>= 1; }
    return a;
}

// ---------- kernel 1: per-timestep coefficient tables (fp64 inside) ----------
// coef[t*NC + f] = w_f^(T-1-t)
// coef[t*NC +10] = g(t) = sum_f pw_f * (1 - w_f^(T-1-t)) / (1 - w_f)
__global__ void coef_kernel(const float* __restrict__ w,
                            const float* __restrict__ pool_w,
                            float* __restrict__ coef) {
    int t = blockIdx.x * blockDim.x + threadIdx.x;
    if (t >= TLEN) return;
    int n = TLEN - 1 - t;
    double g = 0.0;
#pragma unroll
    for (int f = 0; f < NF; ++f) {
        double wf = (double)w[(size_t)f * DD];     // broadcast along D
        double a  = powi_d(wf, n);
        double den = 1.0 - wf;
        double c  = (den > 1e-30) ? (1.0 - a) / den : (double)n;
        g += (double)pool_w[f] * c;
        coef[t * NC + f] = (float)a;
    }
    coef[t * NC + NF]     = (float)g;
    coef[t * NC + NF + 1] = 0.0f;
}

// ---------- kernel 2: streaming pass over inp ----------
// Block (bx, by): columns [bx*1024 .. +1024), rows [by*rows .. +rows).
// rows <= 256 always (C >= 32), so one LDS refill up front.
// Main loop: 4 independent row-streams (quarters) -> 4 outstanding float4
// loads per wave; coef reads as 3x ds_read_b128 per row.
// Partials: part[(by*NC + acc)*DD + d], acc 0=x_sum, 1=pooled, 2+f=h_f.
__global__ __launch_bounds__(256) void pass_kernel(const float* __restrict__ inp,
                                                   const float* __restrict__ coef,
                                                   float* __restrict__ part,
                                                   int rows) {
    __shared__ float sc[256 * NC];
    const int t0 = blockIdx.y * rows;
    const int d  = blockIdx.x * 1024 + threadIdx.x * 4;

    for (int i = threadIdx.x; i < rows * NC; i += 256)
        sc[i] = coef[(size_t)t0 * NC + i];
    __syncthreads();

    float sx=0,sy=0,sz=0,sw=0;           // x_sum
    float px=0,py=0,pz=0,pw4=0;          // pooled_raw
    float hx[NF], hy[NF], hz[NF], hw[NF];
#pragma unroll
    for (int f = 0; f < NF; ++f) { hx[f]=0; hy[f]=0; hz[f]=0; hw[f]=0; }

    auto PROC = [&](int r, float4 x) {
        const float4 c0 = *(const float4*)&sc[r * NC];      // a0..a3
        const float4 c1 = *(const float4*)&sc[r * NC + 4];  // a4..a7
        const float4 c2 = *(const float4*)&sc[r * NC + 8];  // a8,a9,g,pad
        sx += x.x; sy += x.y; sz += x.z; sw += x.w;
        px  = fmaf(c2.z, x.x, px);  py  = fmaf(c2.z, x.y, py);
        pz  = fmaf(c2.z, x.z, pz);  pw4 = fmaf(c2.z, x.w, pw4);
        hx[0]=fmaf(c0.x,x.x,hx[0]); hy[0]=fmaf(c0.x,x.y,hy[0]); hz[0]=fmaf(c0.x,x.z,hz[0]); hw[0]=fmaf(c0.x,x.w,hw[0]);
        hx[1]=fmaf(c0.y,x.x,hx[1]); hy[1]=fmaf(c0.y,x.y,hy[1]); hz[1]=fmaf(c0.y,x.z,hz[1]); hw[1]=fmaf(c0.y,x.w,hw[1]);
        hx[2]=fmaf(c0.z,x.x,hx[2]); hy[2]=fmaf(c0.z,x.y,hy[2]); hz[2]=fmaf(c0.z,x.z,hz[2]); hw[2]=fmaf(c0.z,x.w,hw[2]);
        hx[3]=fmaf(c0.w,x.x,hx[3]); hy[3]=fmaf(c0.w,x.y,hy[3]); hz[3]=fmaf(c0.w,x.z,hz[3]); hw[3]=fmaf(c0.w,x.w,hw[3]);
        hx[4]=fmaf(c1.x,x.x,hx[4]); hy[4]=fmaf(c1.x,x.y,hy[4]); hz[4]=fmaf(c1.x,x.z,hz[4]); hw[4]=fmaf(c1.x,x.w,hw[4]);
        hx[5]=fmaf(c1.y,x.x,hx[5]); hy[5]=fmaf(c1.y,x.y,hy[5]); hz[5]=fmaf(c1.y,x.z,hz[5]); hw[5]=fmaf(c1.y,x.w,hw[5]);
        hx[6]=fmaf(c1.z,x.x,hx[6]); hy[6]=fmaf(c1.z,x.y,hy[6]); hz[6]=fmaf(c1.z,x.z,hz[6]); hw[6]=fmaf(c1.z,x.w,hw[6]);
        hx[7]=fmaf(c1.w,x.x,hx[7]); hy[7]=fmaf(c1.w,x.y,hy[7]); hz[7]=fmaf(c1.w,x.z,hz[7]); hw[7]=fmaf(c1.w,x.w,hw[7]);
        hx[8]=fmaf(c2.x,x.x,hx[8]); hy[8]=fmaf(c2.x,x.y,hy[8]); hz[8]=fmaf(c2.x,x.z,hz[8]); hw[8]=fmaf(c2.x,x.w,hw[8]);
        hx[9]=fmaf(c2.y,x.x,hx[9]); hy[9]=fmaf(c2.y,x.y,hy[9]); hz[9]=fmaf(c2.y,x.z,hz[9]); hw[9]=fmaf(c2.y,x.w,hw[9]);
    };

    const int q = rows >> 2;                       // rows % 4 == 0 always
    const float* ip0 = inp + (size_t)t0 * DD + d;
    const float* ip1 = ip0 + (size_t)q * DD;
    const float* ip2 = ip1 + (size_t)q * DD;
    const float* ip3 = ip2 + (size_t)q * DD;
    for (int r = 0; r < q; ++r) {
        float4 x0 = *(const float4*)ip0; ip0 += DD;
        float4 x1 = *(const float4*)ip1; ip1 += DD;
        float4 x2 = *(const float4*)ip2; ip2 += DD;
        float4 x3 = *(const float4*)ip3; ip3 += DD;
        PROC(r,         x0);
        PROC(r + q,     x1);
        PROC(r + 2 * q, x2);
        PROC(r + 3 * q, x3);
    }

    size_t base = ((size_t)blockIdx.y * NC) * DD + d;
    *(float4*)(part + base)      = make_float4(sx, sy, sz, sw);
    *(float4*)(part + base + DD) = make_float4(px, py, pz, pw4);
#pragma unroll
    for (int f = 0; f < NF; ++f)
        *(float4*)(part + base + (size_t)(2 + f) * DD) =
            make_float4(hx[f], hy[f], hz[f], hw[f]);
}

// ---------- kernel 3: reduce partials over chunks ----------
__global__ void reduce_kernel(const float* __restrict__ part,
                              float* __restrict__ red, int C) {
    int idx = blockIdx.x * blockDim.x + threadIdx.x;  // 0 .. 12*4096
    if (idx >= NACC * DD) return;
    float s = 0.0f;
    for (int c = 0; c < C; ++c)
        s += part[(size_t)c * NC * DD + idx];
    red[idx] = s;
}

// ---------- kernel 4: finalize h_final + avg vector ----------
__global__ void finalize_kernel(const float* __restrict__ red,
                                const float* __restrict__ w,
                                const float* __restrict__ pool_w,
                                const float* __restrict__ pool_b,
                                const float* __restrict__ hidden,
                                float* __restrict__ out,
                                float* __restrict__ avg) {
    int i = blockIdx.x * blockDim.x + threadIdx.x;   // 0..1023
    int d = i * 4;
    float4 xs = *(const float4*)(red + d);
    float4 pl = *(const float4*)(red + DD + d);
    const float invT = 1.0f / (float)TLEN;
#pragma unroll
    for (int f = 0; f < NF; ++f) {
        double wf = (double)w[(size_t)f * DD];
        double wTd = powi_d(wf, TLEN);
        double den = 1.0 - wf;
        double sTd = (den > 1e-30) ? (1.0 - wTd) / den : (double)TLEN;
        float wT = (float)wTd;
        float pwsT = (float)((double)pool_w[f] * sTd);
        float4 hf = *(const float4*)(red + (size_t)(2 + f) * DD + d);
        float4 h0 = *(const float4*)(hidden + (size_t)f * DD + d);
        hf.x = fmaf(wT, h0.x, hf.x); hf.y = fmaf(wT, h0.y, hf.y);
        hf.z = fmaf(wT, h0.z, hf.z); hf.w = fmaf(wT, h0.w, hf.w);
        pl.x = fmaf(pwsT, h0.x, pl.x); pl.y = fmaf(pwsT, h0.y, pl.y);
        pl.z = fmaf(pwsT, h0.z, pl.z); pl.w = fmaf(pwsT, h0.w, pl.w);
        float* o = out + 10 + (size_t)f * DD + d;   // 40B-misaligned -> scalar
        o[0] = hf.x; o[1] = hf.y; o[2] = hf.z; o[3] = hf.w;
    }
    float pb = pool_b[0];
    avg[d+0] = xs.x * invT; avg[d+1] = xs.y * invT;
    avg[d+2] = xs.z * invT; avg[d+3] = xs.w * invT;
    avg[DD + d + 0] = pl.x * invT + pb; avg[DD + d + 1] = pl.y * invT + pb;
    avg[DD + d + 2] = pl.z * invT + pb; avg[DD + d + 3] = pl.w * invT + pb;
}

// ---------- kernel 5: GEMV  hid = relu(i2o_w @ avg + i2o_b) ----------
__global__ __launch_bounds__(256) void gemv_kernel(const float* __restrict__ W,
                                                   const float* __restrict__ b,
                                                   const float* __restrict__ avg,
                                                   float* __restrict__ hid) {
    int row  = blockIdx.x * 4 + (threadIdx.x >> 6);
    int lane = threadIdx.x & 63;
    const float* wr = W + (size_t)row * (2 * DD);
    float acc = 0.0f;
#pragma unroll 8
    for (int j0 = 0; j0 < 32; ++j0) {
        int j = j0 * 256 + lane * 4;
        float4 wv = *(const float4*)(wr + j);
        float4 av = *(const float4*)(avg + j);
        acc = fmaf(wv.x, av.x, acc); acc = fmaf(wv.y, av.y, acc);
        acc = fmaf(wv.z, av.z, acc); acc = fmaf(wv.w, av.w, acc);
    }
    for (int off = 32; off; off >>= 1) acc += __shfl_down(acc, off, 64);
    if (lane == 0) hid[row] = fmaxf(acc + b[row], 0.0f);
}

// ---------- kernel 6: final 10-way dot ----------
__global__ void out_kernel(const float* __restrict__ hid,
                           const float* __restrict__ ow,
                           const float* __restrict__ ob,
                           float* __restrict__ out) {
    __shared__ float redl[256];
    int o = blockIdx.x;
    float acc = 0.0f;
    for (int h = threadIdx.x; h < DD; h += 256)
        acc = fmaf(hid[h], ow[(size_t)o * DD + h], acc);
    redl[threadIdx.x] = acc;
    __syncthreads();
    for (int s = 128; s; s >>= 1) {
        if (threadIdx.x < s) redl[threadIdx.x] += redl[threadIdx.x + s];
        __syncthreads();
    }
    if (threadIdx.x == 0) out[o] = redl[0] + ob[o];
}

extern "C" void kernel_launch(void* const* d_in, const int* in_sizes, int n_in,
                              void* d_out, int out_size, void* d_ws, size_t ws_size,
                              hipStream_t stream) {
    const float* inp    = (const float*)d_in[0];
    const float* hidden = (const float*)d_in[1];
    const float* w      = (const float*)d_in[2];
    const float* pw     = (const float*)d_in[3];
    const float* pb     = (const float*)d_in[4];
    const float* i2o_w  = (const float*)d_in[5];
    const float* i2o_b  = (const float*)d_in[6];
    const float* o_w    = (const float*)d_in[7];
    const float* o_b    = (const float*)d_in[8];
    float* out = (float*)d_out;
    float* ws  = (float*)d_ws;

    // workspace layout (floats)
    float* coef = ws;                 // 8192*12 = 98304
    float* red  = ws + 98304;         // 12*4096 = 49152
    float* avg  = ws + 147456;        // 8192
    float* hid  = ws + 155648;        // 4096
    float* part = ws + 159744;        // C*12*4096

    // chunk count C (rows = TLEN/C <= 256, multiple of 4)
    int C = 128;
    while (C > 32) {
        size_t need = (159744 + (size_t)C * NC * DD) * sizeof(float);
        if (need <= ws_size) break;
        C >>= 1;
    }
    int rows = TLEN / C;

    coef_kernel<<<TLEN / 256, 256, 0, stream>>>(w, pw, coef);
    pass_kernel<<<dim3(4, C), 256, 0, stream>>>(inp, coef, part, rows);
    reduce_kernel<<<(NACC * DD + 255) / 256, 256, 0, stream>>>(part, red, C);
    finalize_kernel<<<4, 256, 0, stream>>>(red, w, pw, pb, hidden, out, avg);
    gemv_kernel<<<DD / 4, 256, 0, stream>>>(i2o_w, i2o_b, avg, hid);
    out_kernel<<<10, 256, 0, stream>>>(hid, o_w, o_b, out);
}